// Round 2
// baseline (996.080 us; speedup 1.0000x reference)
//
#include <hip/hip_runtime.h>
#include <stdint.h>

typedef __attribute__((ext_vector_type(8))) short short8;
typedef __attribute__((ext_vector_type(4))) float f32x4;
typedef __attribute__((ext_vector_type(4))) unsigned short us4;

__device__ __forceinline__ unsigned short f2bf(float f){
  union{float f; unsigned u;} v; v.f = f;
  unsigned r = v.u + 0x7FFFu + ((v.u >> 16) & 1u);
  return (unsigned short)(r >> 16);
}
__device__ __forceinline__ float bflo(unsigned u){
  union{unsigned a; float f;} t; t.a = (u & 0xFFFFu) << 16; return t.f;
}
__device__ __forceinline__ float bfhi(unsigned u){
  union{unsigned a; float f;} t; t.a = u & 0xFFFF0000u; return t.f;
}

// ---------------- pack conv_w -> wA [ks=18][m=128][kk=32] bf16, k=(dh*3+dw)*64+cin
__global__ __launch_bounds__(256) void k_prep(const float* __restrict__ cw,
                                              unsigned short* __restrict__ wA){
  int i = blockIdx.x*256 + threadIdx.x;
  if(i >= 18*128*32) return;
  int kk = i & 31, m = (i >> 5) & 127, ks = i >> 12;
  int k = ks*32 + kk;
  int pos = k >> 6, cin = k & 63;
  int dh = pos/3, dw = pos - dh*3;
  wA[i] = f2bf(cw[((m*64 + cin)*3 + dh)*3 + dw]);
}

// ---------------- x fp32 [b][cin][hw] -> xt bf16 [b][hw][cin] with 16B-granule XOR swizzle
__global__ __launch_bounds__(256) void k_cvt(const float* __restrict__ x,
                                             unsigned short* __restrict__ xt){
  const int b = blockIdx.y;
  const int hw = blockIdx.x*256 + threadIdx.x;
  const float* xb = x + (size_t)b*64*32768 + hw;
  unsigned short* ob = xt + ((size_t)b*32768 + hw)*64;
  const int sw = hw & 7;
  #pragma unroll
  for(int g=0; g<8; ++g){
    unsigned short v[8];
    #pragma unroll
    for(int j=0;j<8;++j) v[j] = f2bf(xb[(size_t)(8*g+j)*32768]);
    *(short8*)(ob + (size_t)((g ^ sw)*8)) = *(const short8*)v;
  }
}

// ---------------- implicit-GEMM conv: block=(4 rows, b). craw layout [b][hw][c] bf16.
__global__ __launch_bounds__(256,2) void k_conv2(
    const unsigned short* __restrict__ xt, const unsigned short* __restrict__ wA,
    unsigned short* __restrict__ craw)
{
  const int b = blockIdx.y;
  const int h0 = blockIdx.x * 4;
  __shared__ __align__(16) unsigned short xs[6*64*64];  // 48 KB, swizzled global layout
  const int t = threadIdx.x;
  const int lane = t & 63, wv = t >> 6;
  {
    const unsigned short* xb = xt + (size_t)b*32768*64;
    for(int i=0;i<12;++i){
      int ch = wv*12 + i;                 // 48 chunks of 1 KB
      int r = ch >> 3, col = ch & 7;
      int hin = h0 - 1 + r;
      hin = hin < 0 ? 1 : (hin > 511 ? 510 : hin);   // reflect pad
      const unsigned short* gsrc = xb + (size_t)hin*4096 + col*512 + lane*8;
      __builtin_amdgcn_global_load_lds(
          (const __attribute__((address_space(1))) unsigned int*)(const void*)gsrc,
          (__attribute__((address_space(3))) unsigned int*)(void*)&xs[ch*512],
          16, 0, 0);
    }
  }
  __syncthreads();
  const int r15 = lane & 15, quad = lane >> 4;
  f32x4 acc[8][4];
  #pragma unroll
  for(int mt=0;mt<8;++mt)
    #pragma unroll
    for(int nt=0;nt<4;++nt){ f32x4 z = {0.f,0.f,0.f,0.f}; acc[mt][nt] = z; }
  short8 a_cur[8], a_nxt[8];
  const unsigned short* wb = wA + r15*32 + quad*8;
  #pragma unroll
  for(int mt=0;mt<8;++mt) a_cur[mt] = *(const short8*)(wb + mt*512);
  for(int ks=0; ks<18; ++ks){
    if(ks < 17){
      const unsigned short* wk = wb + (ks+1)*4096;
      #pragma unroll
      for(int mt=0;mt<8;++mt) a_nxt[mt] = *(const short8*)(wk + mt*512);
    }
    const int pos = ks >> 1;
    const int dh = pos < 3 ? 0 : (pos < 6 ? 1 : 2);
    const int dw = pos - dh*3;
    const int g = (ks & 1)*4 + quad;
    const int rr = wv + dh;
    short8 bfr[4];
    #pragma unroll
    for(int nt=0;nt<4;++nt){
      int w = nt*16 + r15;
      int wi = w + dw - 1;
      wi = wi < 0 ? 1 : (wi > 63 ? 62 : wi);         // reflect pad
      bfr[nt] = *(const short8*)&xs[(rr*64 + wi)*64 + ((g ^ (wi & 7))*8)];
    }
    #pragma unroll
    for(int mt=0;mt<8;++mt){
      #pragma unroll
      for(int nt=0;nt<4;++nt)
        acc[mt][nt] = __builtin_amdgcn_mfma_f32_16x16x32_bf16(a_cur[mt], bfr[nt], acc[mt][nt], 0,0,0);
    }
    #pragma unroll
    for(int mt=0;mt<8;++mt) a_cur[mt] = a_nxt[mt];
  }
  // epilogue: D col=lane&15 -> w, row=quad*4+rg -> cout. Pack 4 couts -> 8B store.
  const size_t orow = (size_t)b*32768 + (size_t)(h0 + wv)*64;
  #pragma unroll
  for(int nt=0;nt<4;++nt){
    int w = nt*16 + r15;
    unsigned short* dst = craw + (orow + w)*128 + quad*4;
    #pragma unroll
    for(int mt=0;mt<8;++mt){
      us4 v;
      v[0] = f2bf(acc[mt][nt][0]); v[1] = f2bf(acc[mt][nt][1]);
      v[2] = f2bf(acc[mt][nt][2]); v[3] = f2bf(acc[mt][nt][3]);
      *(us4*)(dst + mt*16) = v;
    }
  }
}

// ---------------- BN1 raw stats over craw (per cout sum/sumsq)
__global__ __launch_bounds__(256) void k_s1raw(const unsigned short* __restrict__ craw,
                                               float* __restrict__ Ssum, float* __restrict__ Ssq){
  const int blk = blockIdx.x;            // 1024 blocks x 512 rows
  const int t = threadIdx.x, c2 = t & 63, sub = t >> 6;
  const unsigned* base = (const unsigned*)craw + (size_t)blk*512*64 + c2;
  float s0=0.f,q0=0.f,s1v=0.f,q1v=0.f;
  for(int i=0;i<128;++i){
    unsigned u = base[(size_t)(sub + 4*i)*64];
    float a = bflo(u), bb = bfhi(u);
    s0 += a; q0 += a*a; s1v += bb; q1v += bb*bb;
  }
  __shared__ float rs_[128], rq_[128];
  if(t < 128){ rs_[t]=0.f; rq_[t]=0.f; }
  __syncthreads();
  atomicAdd(&rs_[c2*2], s0);   atomicAdd(&rq_[c2*2], q0);
  atomicAdd(&rs_[c2*2+1], s1v); atomicAdd(&rq_[c2*2+1], q1v);
  __syncthreads();
  if(t < 128){ atomicAdd(&Ssum[t], rs_[t]); atomicAdd(&Ssq[t], rq_[t]); }
}

__global__ void k_bn1fin(const float* __restrict__ Ssum, const float* __restrict__ Ssq,
                         const float* __restrict__ g1, const float* __restrict__ b1,
                         float* __restrict__ s1, float* __restrict__ t1){
  int c = threadIdx.x; if(c >= 128) return;
  const double N = 524288.0;
  double mu = (double)Ssum[c]/N, var = (double)Ssq[c]/N - mu*mu;
  float sc = (float)((double)g1[c]/sqrt(var + 1e-5));
  s1[c] = sc; t1[c] = (float)((double)b1[c] - mu*(double)sc);
}

// ---------------- h=relu(bn1(craw)); xmT[b][h][c]=mean_w h; Sh/Qh slots; LN slots
__global__ __launch_bounds__(256) void k_passB(
    const unsigned short* __restrict__ craw, const float* __restrict__ s1,
    const float* __restrict__ t1, float* __restrict__ xmT,
    float* __restrict__ ShS, float* __restrict__ QhS,
    float* __restrict__ lnSS, float* __restrict__ lnQS)
{
  const int h = blockIdx.x, b = blockIdx.y;
  const int t = threadIdx.x, c2 = t & 63, sub = t >> 6;
  const int c0 = c2*2, c1 = c0+1;
  const float A0 = s1[c0], B0 = t1[c0], A1 = s1[c1], B1 = t1[c1];
  const unsigned* base = (const unsigned*)craw + ((size_t)b*32768 + (size_t)h*64)*64 + c2;
  float sm0=0.f, sm1=0.f, q0=0.f, q1=0.f;
  for(int i=0;i<16;++i){
    unsigned u = base[(size_t)(sub + 4*i)*64];
    float v0 = fmaxf(A0*bflo(u) + B0, 0.f);
    float v1 = fmaxf(A1*bfhi(u) + B1, 0.f);
    sm0 += v0; sm1 += v1; q0 += v0*v0; q1 += v1*v1;
  }
  __shared__ float red_s[128], red_q[128];
  if(t < 128){ red_s[t]=0.f; red_q[t]=0.f; }
  __syncthreads();
  atomicAdd(&red_s[c0], sm0); atomicAdd(&red_s[c1], sm1);
  atomicAdd(&red_q[c0], q0);  atomicAdd(&red_q[c1], q1);
  __syncthreads();
  if(t < 128){
    float S = red_s[t];
    float xmv = S * (1.f/64.f);
    xmT[((size_t)b*512 + h)*128 + t] = xmv;
    int slot = h & 63;
    atomicAdd(&ShS[t*64 + slot], S);
    atomicAdd(&QhS[t*64 + slot], red_q[t]);
    float l1 = xmv, l2 = xmv*xmv;
    #pragma unroll
    for(int m=1;m<64;m<<=1){ l1 += __shfl_xor(l1, m); l2 += __shfl_xor(l2, m); }
    if((t & 63) == 0){
      atomicAdd(&lnSS[b*32 + (h & 31)], l1);
      atomicAdd(&lnQS[b*32 + (h & 31)], l2);
    }
  }
}

// ---------------- scores f[b,h,k] = xn.xn/sqrt(C), xn normalized inline from xmT
__global__ __launch_bounds__(256) void k_f(const float* __restrict__ xmT,
    const float* __restrict__ lnSS, const float* __restrict__ lnQS, float* __restrict__ f)
{
  const int kt = blockIdx.x, ht = blockIdx.y, b = blockIdx.z;
  __shared__ float Xh[64*129], Xk[64*129];   // [h][c] pitch 129
  __shared__ float musd[2];
  const int t = threadIdx.x;
  if(t == 0){
    float S=0.f, Q=0.f;
    for(int i=0;i<32;++i){ S += lnSS[b*32+i]; Q += lnQS[b*32+i]; }
    float mu = S * (1.f/65536.f);
    float var = Q * (1.f/65536.f) - mu*mu;
    musd[0] = mu; musd[1] = rsqrtf(var + 1e-5f);
  }
  __syncthreads();
  const float mu = musd[0], rs = musd[1];
  const int h0 = ht*64, k0 = kt*64;
  for(int i=0;i<8;++i){
    int idx = t + i*256;             // 2048: row(64) x cq(32)
    int row = idx >> 5, cq = idx & 31;
    f32x4 vh = *(const f32x4*)&xmT[((size_t)b*512 + h0 + row)*128 + cq*4];
    f32x4 vk = *(const f32x4*)&xmT[((size_t)b*512 + k0 + row)*128 + cq*4];
    #pragma unroll
    for(int k=0;k<4;++k){
      Xh[row*129 + cq*4 + k] = (vh[k] - mu)*rs;
      Xk[row*129 + cq*4 + k] = (vk[k] - mu)*rs;
    }
  }
  __syncthreads();
  const int tx = t & 15, ty = t >> 4;
  float acc[4][4] = {{0}};
  for(int c=0;c<128;++c){
    float a[4], bb[4];
    #pragma unroll
    for(int i=0;i<4;++i) a[i] = Xh[(ty*4+i)*129 + c];
    #pragma unroll
    for(int j=0;j<4;++j) bb[j] = Xk[(tx*4+j)*129 + c];
    #pragma unroll
    for(int i=0;i<4;++i)
      #pragma unroll
      for(int j=0;j<4;++j) acc[i][j] += a[i]*bb[j];
  }
  const float s = 0.088388347648318447f;
  #pragma unroll
  for(int i=0;i<4;++i){
    f32x4 o;
    #pragma unroll
    for(int j=0;j<4;++j) o[j] = acc[i][j]*s;
    *(f32x4*)&f[((size_t)b*512 + h0 + ty*4 + i)*512 + k0 + tx*4] = o;
  }
}

// ---------------- softmax over last axis (row of 512 per wave)
__global__ __launch_bounds__(256) void k_sm(float* __restrict__ f)
{
  const int bid = blockIdx.x;
  const int b = bid >> 7, h4 = bid & 127;
  const int t = threadIdx.x, wv = t >> 6, l = t & 63;
  float* row = f + ((size_t)b*512 + h4*4 + wv)*512;
  f32x4 v0 = *(const f32x4*)&row[l*8];
  f32x4 v1 = *(const f32x4*)&row[l*8 + 4];
  float mx = v0[0];
  #pragma unroll
  for(int j=1;j<4;++j) mx = fmaxf(mx, v0[j]);
  #pragma unroll
  for(int j=0;j<4;++j) mx = fmaxf(mx, v1[j]);
  #pragma unroll
  for(int m=1;m<64;m<<=1) mx = fmaxf(mx, __shfl_xor(mx, m));
  float sum = 0.f;
  #pragma unroll
  for(int j=0;j<4;++j){ v0[j] = __expf(v0[j]-mx); sum += v0[j]; }
  #pragma unroll
  for(int j=0;j<4;++j){ v1[j] = __expf(v1[j]-mx); sum += v1[j]; }
  #pragma unroll
  for(int m=1;m<64;m<<=1) sum += __shfl_xor(sum, m);
  float inv = 1.f / sum;
  #pragma unroll
  for(int j=0;j<4;++j){ v0[j] *= inv; v1[j] *= inv; }
  *(f32x4*)&row[l*8] = v0;
  *(f32x4*)&row[l*8+4] = v1;
}

// ---------------- y1[b,m,k] = g_w @ xn + g_b (xn normalized inline)
__global__ __launch_bounds__(256) void k_y1(
    const float* __restrict__ xmT, const float* __restrict__ lnSS, const float* __restrict__ lnQS,
    const float* __restrict__ gw, const float* __restrict__ gb, float* __restrict__ y1)
{
  const int kt = blockIdx.x, b = blockIdx.y;
  __shared__ __align__(16) float GT[128*128];
  __shared__ __align__(16) float XN[128*68];
  __shared__ float musd[2];
  const int t = threadIdx.x;
  if(t == 0){
    float S=0.f, Q=0.f;
    for(int i=0;i<32;++i){ S += lnSS[b*32+i]; Q += lnQS[b*32+i]; }
    float mu = S * (1.f/65536.f);
    float var = Q * (1.f/65536.f) - mu*mu;
    musd[0] = mu; musd[1] = rsqrtf(var + 1e-5f);
  }
  __syncthreads();
  const float mu = musd[0], rs = musd[1];
  const int k0 = kt*64;
  for(int i=0;i<64;++i){
    int idx = t + i*256;
    int o = idx & 127, c = idx >> 7;
    GT[c*128 + o] = gw[o*128 + c];
  }
  for(int i=0;i<32;++i){
    int idx = t + i*256;                // 8192: k(64) x c(128)
    int c = idx & 127, k = idx >> 7;
    XN[c*68 + k] = (xmT[((size_t)b*512 + k0 + k)*128 + c] - mu)*rs;
  }
  __syncthreads();
  const int tx = t & 15, ty = t >> 4;
  float acc[8][4] = {{0}};
  for(int c=0;c<128;++c){
    f32x4 a0 = *(const f32x4*)&GT[c*128 + ty*8];
    f32x4 a1 = *(const f32x4*)&GT[c*128 + ty*8 + 4];
    f32x4 bv = *(const f32x4*)&XN[c*68 + tx*4];
    #pragma unroll
    for(int j=0;j<4;++j){
      #pragma unroll
      for(int i=0;i<4;++i){ acc[i][j] += a0[i]*bv[j]; acc[i+4][j] += a1[i]*bv[j]; }
    }
  }
  #pragma unroll
  for(int i=0;i<8;++i){
    int m = ty*8 + i;
    float bias = gb[m];
    f32x4 o;
    #pragma unroll
    for(int j=0;j<4;++j) o[j] = acc[i][j] + bias;
    *(f32x4*)&y1[((size_t)b*128 + m)*512 + k0 + tx*4] = o;
  }
}

// ---------------- y2t[b,h,m] = sum_k f[b,h,k]*y1[b,m,k]
__global__ __launch_bounds__(256) void k_y2(
    const float* __restrict__ f, const float* __restrict__ y1, float* __restrict__ y2t)
{
  const int ht = blockIdx.x, b = blockIdx.y;
  __shared__ __align__(16) float FT[64*36];
  __shared__ __align__(16) float Y1T[64*132];
  const int t = threadIdx.x;
  const int h0 = ht*32;
  const int tx = t & 15, ty = t >> 4;
  float acc[2][8] = {{0}};
  for(int kc=0;kc<8;++kc){
    int k0 = kc*64;
    __syncthreads();
    for(int i=0;i<8;++i){
      int idx = t + i*256;
      int k = idx & 63, hh = idx >> 6;
      FT[k*36 + hh] = f[((size_t)b*512 + h0 + hh)*512 + k0 + k];
    }
    for(int i=0;i<32;++i){
      int idx = t + i*256;
      int k = idx & 63, m = idx >> 6;
      Y1T[k*132 + m] = y1[((size_t)b*128 + m)*512 + k0 + k];
    }
    __syncthreads();
    for(int kk=0;kk<64;++kk){
      float a0 = FT[kk*36 + ty*2], a1 = FT[kk*36 + ty*2+1];
      f32x4 b0 = *(const f32x4*)&Y1T[kk*132 + tx*8];
      f32x4 b1 = *(const f32x4*)&Y1T[kk*132 + tx*8 + 4];
      #pragma unroll
      for(int j=0;j<4;++j){
        acc[0][j]   += a0*b0[j]; acc[1][j]   += a1*b0[j];
        acc[0][j+4] += a0*b1[j]; acc[1][j+4] += a1*b1[j];
      }
    }
  }
  #pragma unroll
  for(int i=0;i<2;++i){
    int h = h0 + ty*2 + i;
    f32x4 o0, o1;
    #pragma unroll
    for(int j=0;j<4;++j){ o0[j]=acc[i][j]; o1[j]=acc[i][j+4]; }
    float* dst = y2t + ((size_t)b*512 + h)*128 + tx*8;
    *(f32x4*)dst = o0;
    *(f32x4*)(dst+4) = o1;
  }
}

// ---------------- y3T[b,h,o] = out_w @ y2 + out_b, fused BN2-residual stats
__global__ __launch_bounds__(256) void k_y3(
    const float* __restrict__ y2t, const float* __restrict__ ow, const float* __restrict__ obv,
    const float* __restrict__ xmT, float* __restrict__ y3T,
    float* __restrict__ Sy, float* __restrict__ Syy, float* __restrict__ Sxy)
{
  const int ht = blockIdx.x, b = blockIdx.y;
  __shared__ __align__(16) float WT[128*128];
  __shared__ __align__(16) float Y2[128*36];
  __shared__ float ot[32*130];
  const int t = threadIdx.x;
  const int h0 = ht*32;
  for(int i=0;i<64;++i){
    int idx = t + i*256;
    int o = idx & 127, m = idx >> 7;
    WT[m*128 + o] = ow[o*128 + m];
  }
  for(int i=0;i<16;++i){
    int idx = t + i*256;
    int m = idx & 127, hh = idx >> 7;
    Y2[m*36 + hh] = y2t[((size_t)b*512 + h0 + hh)*128 + m];
  }
  __syncthreads();
  const int tx = t & 15, ty = t >> 4;
  float acc[8][2] = {{0}};
  for(int m=0;m<128;++m){
    f32x4 a0 = *(const f32x4*)&WT[m*128 + ty*8];
    f32x4 a1 = *(const f32x4*)&WT[m*128 + ty*8 + 4];
    float b0 = Y2[m*36 + tx*2], b1v = Y2[m*36 + tx*2 + 1];
    #pragma unroll
    for(int i=0;i<4;++i){
      acc[i][0]   += a0[i]*b0; acc[i][1]   += a0[i]*b1v;
      acc[i+4][0] += a1[i]*b0; acc[i+4][1] += a1[i]*b1v;
    }
  }
  float sy[8], syy[8], sxy[8];
  #pragma unroll
  for(int i=0;i<8;++i){
    int o = ty*8 + i;
    float bias = obv[o];
    sy[i]=0.f; syy[i]=0.f; sxy[i]=0.f;
    #pragma unroll
    for(int j=0;j<2;++j){
      int hh = tx*2 + j;
      float v = acc[i][j] + bias;
      ot[hh*130 + o] = v;
      float xmv = xmT[((size_t)b*512 + h0 + hh)*128 + o];
      sy[i] += v; syy[i] += v*v; sxy[i] += v*xmv;
    }
  }
  #pragma unroll
  for(int i=0;i<8;++i){
    #pragma unroll
    for(int m=1;m<16;m<<=1){
      sy[i] += __shfl_xor(sy[i], m); syy[i] += __shfl_xor(syy[i], m); sxy[i] += __shfl_xor(sxy[i], m);
    }
  }
  if(tx == 0){
    #pragma unroll
    for(int i=0;i<8;++i){
      int o = ty*8 + i;
      atomicAdd(&Sy[o], sy[i]); atomicAdd(&Syy[o], syy[i]); atomicAdd(&Sxy[o], sxy[i]);
    }
  }
  __syncthreads();
  for(int i=0;i<4;++i){
    int flat = t + i*256;               // 1024 float4: hh(32) x oq(32)
    int hh = flat >> 5, oq = flat & 31;
    f32x4 v;
    #pragma unroll
    for(int k=0;k<4;++k) v[k] = ot[hh*130 + oq*4 + k];
    *(f32x4*)&y3T[((size_t)b*512 + h0 + hh)*128 + oq*4] = v;
  }
}

__global__ void k_bn2fin(const float* __restrict__ ShS, const float* __restrict__ QhS,
    const float* __restrict__ Sy, const float* __restrict__ Syy, const float* __restrict__ Sxy,
    const float* __restrict__ g2, const float* __restrict__ b2,
    float* __restrict__ s2, float* __restrict__ t2)
{
  int c = threadIdx.x; if(c >= 128) return;
  double Sh = 0.0, Qh = 0.0;
  for(int s=0;s<64;++s){ Sh += (double)ShS[c*64+s]; Qh += (double)QhS[c*64+s]; }
  const double N = 524288.0;
  double S2 = Sh + 64.0*(double)Sy[c];
  double Q2 = Qh + 128.0*(double)Sxy[c] + 64.0*(double)Syy[c];
  double mu = S2/N, var = Q2/N - mu*mu;
  float sc = (float)((double)g2[c]/sqrt(var + 1e-5));
  s2[c] = sc; t2[c] = (float)((double)b2[c] - mu*(double)sc);
}

// ---------------- out = silu(bn2(relu(bn1(craw)) + y3)); LDS transpose for coalesced store
__global__ __launch_bounds__(256) void k_final(
    const unsigned short* __restrict__ craw, const float* __restrict__ s1, const float* __restrict__ t1,
    const float* __restrict__ y3T, const float* __restrict__ s2, const float* __restrict__ t2,
    float* __restrict__ out)
{
  const int h = blockIdx.x, b = blockIdx.y;
  __shared__ float tile[128*65];
  __shared__ float yl[128], p1a[128], p1b[128], p2a[128], p2b[128];
  const int t = threadIdx.x;
  if(t < 128){
    yl[t] = y3T[((size_t)b*512 + h)*128 + t];
    p1a[t] = s1[t]; p1b[t] = t1[t]; p2a[t] = s2[t]; p2b[t] = t2[t];
  }
  __syncthreads();
  const int c2 = t & 63, sub = t >> 6;
  const int c0 = c2*2, c1 = c0+1;
  const float A0 = p1a[c0], B0 = p1b[c0], A1 = p1a[c1], B1 = p1b[c1];
  const float C0 = p2a[c0], D0 = p2b[c0], C1 = p2a[c1], D1 = p2b[c1];
  const float Y0 = yl[c0], Y1 = yl[c1];
  const unsigned* base = (const unsigned*)craw + ((size_t)b*32768 + (size_t)h*64)*64 + c2;
  for(int i=0;i<16;++i){
    int w = sub + 4*i;
    unsigned u = base[(size_t)w*64];
    float h0v = fmaxf(A0*bflo(u) + B0, 0.f) + Y0;
    float h1v = fmaxf(A1*bfhi(u) + B1, 0.f) + Y1;
    float z0 = C0*h0v + D0, z1 = C1*h1v + D1;
    tile[c0*65 + w] = z0 / (1.f + __expf(-z0));
    tile[c1*65 + w] = z1 / (1.f + __expf(-z1));
  }
  __syncthreads();
  for(int j=0;j<8;++j){
    int flat = t + 256*j;               // 2048: c(128) x seg(16)
    int c = flat >> 4, seg = flat & 15;
    f32x4 v;
    #pragma unroll
    for(int k=0;k<4;++k) v[k] = tile[c*65 + seg*4 + k];
    *(f32x4*)&out[(((size_t)b*128 + c)*512 + h)*64 + seg*4] = v;
  }
}

extern "C" void kernel_launch(void* const* d_in, const int* in_sizes, int n_in,
                              void* d_out, int out_size, void* d_ws, size_t ws_size,
                              hipStream_t stream)
{
  const float* x      = (const float*)d_in[0];
  const float* conv_w = (const float*)d_in[1];
  const float* bn1_g  = (const float*)d_in[2];
  const float* bn1_b  = (const float*)d_in[3];
  const float* g_w    = (const float*)d_in[4];
  const float* g_b    = (const float*)d_in[5];
  const float* out_w  = (const float*)d_in[6];
  const float* out_b  = (const float*)d_in[7];
  const float* bn2_g  = (const float*)d_in[8];
  const float* bn2_b  = (const float*)d_in[9];
  float* out = (float*)d_out;
  char* ws = (char*)d_ws;

  // ---- ws layout (high-water ~138.5 MB) ----
  float* Ssum = (float*)(ws + 0);        // 128
  float* Ssq  = (float*)(ws + 512);      // 128
  float* Sy   = (float*)(ws + 1024);     // 128
  float* Syy  = (float*)(ws + 1536);     // 128
  float* Sxy  = (float*)(ws + 2048);     // 128
  float* lnSS = (float*)(ws + 2560);     // 16*32
  float* lnQS = (float*)(ws + 4608);     // 16*32
  float* ShS  = (float*)(ws + 6656);     // 128*64
  float* QhS  = (float*)(ws + 39424);    // 128*64  -> zero region ends 72192
  float* s1   = (float*)(ws + 72192);
  float* t1   = (float*)(ws + 72704);
  float* s2   = (float*)(ws + 73216);
  float* t2   = (float*)(ws + 73728);
  float* y3T  = (float*)(ws + 74240);                 // 4 MB
  unsigned short* craw = (unsigned short*)(ws + 4268544);  // 134.2 MB

  // ---- dead-before-k_final intermediates live in d_out (268 MB) ----
  char* ob = (char*)d_out;
  unsigned short* xt  = (unsigned short*)(ob + 0);          // 67.1 MB
  float* xmT = (float*)(ob + 67108864);                     // 4 MB
  float* f   = (float*)(ob + 71303168);                     // 16 MB
  float* y1  = (float*)(ob + 88080384);                     // 4 MB
  float* y2t = (float*)(ob + 92274688);                     // 4 MB
  unsigned short* wA = (unsigned short*)(ob + 96468992);    // 147 KB

  hipMemsetAsync(ws, 0, 72192, stream);
  hipLaunchKernelGGL(k_prep,   dim3(288),      dim3(256), 0, stream, conv_w, wA);
  hipLaunchKernelGGL(k_cvt,    dim3(128,16),   dim3(256), 0, stream, x, xt);
  hipLaunchKernelGGL(k_conv2,  dim3(128,16),   dim3(256), 0, stream, xt, wA, craw);
  hipLaunchKernelGGL(k_s1raw,  dim3(1024),     dim3(256), 0, stream, craw, Ssum, Ssq);
  hipLaunchKernelGGL(k_bn1fin, dim3(1),        dim3(128), 0, stream, Ssum, Ssq, bn1_g, bn1_b, s1, t1);
  hipLaunchKernelGGL(k_passB,  dim3(512,16),   dim3(256), 0, stream, craw, s1, t1, xmT, ShS, QhS, lnSS, lnQS);
  hipLaunchKernelGGL(k_f,      dim3(8,8,16),   dim3(256), 0, stream, xmT, lnSS, lnQS, f);
  hipLaunchKernelGGL(k_sm,     dim3(2048),     dim3(256), 0, stream, f);
  hipLaunchKernelGGL(k_y1,     dim3(8,16),     dim3(256), 0, stream, xmT, lnSS, lnQS, g_w, g_b, y1);
  hipLaunchKernelGGL(k_y2,     dim3(16,16),    dim3(256), 0, stream, f, y1, y2t);
  hipLaunchKernelGGL(k_y3,     dim3(16,16),    dim3(256), 0, stream, y2t, out_w, out_b, xmT, y3T, Sy, Syy, Sxy);
  hipLaunchKernelGGL(k_bn2fin, dim3(1),        dim3(128), 0, stream, ShS, QhS, Sy, Syy, Sxy, bn2_g, bn2_b, s2, t2);
  hipLaunchKernelGGL(k_final,  dim3(512,16),   dim3(256), 0, stream, craw, s1, t1, y3T, s2, t2, out);
}